// Round 19
// baseline (3947.863 us; speedup 1.0000x reference)
//
#include <hip/hip_runtime.h>
#include <stdint.h>

// Persistent-LSTM, round 19: r15 exchange protocol VERBATIM + zbuf-free
// compute path (tile-split waves instead of K-split).
//  - 256 WGs x 128 threads (2 waves). g = bid&3 (rows 16g..16g+15, XCD-pair
//    locality), m = bid>>2 (u-cols 8m..8m+7).
//  - COLUMN REMAP: WG's 32 z-cols arranged as 2 tiles of 16; tile tau holds
//    4 gates x 4 u's (col n: gate=n>>2, u = m*8 + tau*4 + (n&3)). Wave w owns
//    tile w over the FULL K=768 (24 MFMAs/wave, same count as r15's K-split).
//    => each wave's acc holds COMPLETE z; the gates-of-a-u gather is
//    cross-LANE (16 __shfl) not cross-wave => zbuf + combine barrier + LDS
//    round-trip deleted from the loop-carried chain.
//  - Exchange protocol = r15 (ablation-proven optimum): hbuf plain bf16
//    [2][64][512]; spread tags [4][64][16]; wave-0 poll w/ counted vmcnt;
//    release = h store -> vmcnt(0) ack -> s_barrier -> tag -> probe -> out.
//  - vmcnt bookkeeping (per wave): tail leaves tag(1,w0)+probe(1,w0)+out(4)
//    => head poll waits vmcnt(4). Head issues h(16)+xpf(16); h certified by
//    vmcnt(24) (first 8) / vmcnt(16) (all; outs retire first, in-order).
//  - Gate math: lanes with (l&15)<4 own (4 rows x 1 u); others' results
//    unused. creg[4] per gm-lane. Numerics: same bf16 inputs; fp32
//    accumulation order differs from r15 (x-then-h single chain) -- harmless.

#define Tt   1024
#define Uu   512
#define G4U  2048
#define NWG  256
#define NTHR 128
#define TAGSTRIDE 16                               // u32s per tag line (64 B)

#define WF_ELEMS (2 * 24 * 64 * 8)                 // [tile][kt][lane][8] 48 KB
#define WF_BYTES (WF_ELEMS * 2)
#define SMEM_BYTES WF_BYTES

typedef short  bf16x8 __attribute__((ext_vector_type(8)));
typedef float  f32x4  __attribute__((ext_vector_type(4)));
typedef int    int4v  __attribute__((ext_vector_type(4)));
typedef unsigned int u32;

__device__ __forceinline__ unsigned short f2bf(float f) {
  u32 u = __builtin_bit_cast(u32, f);
  u += 0x7fffu + ((u >> 16) & 1u);                 // RNE (finite inputs)
  return (unsigned short)(u >> 16);
}

// sc1 = agent scope (IF$); plain = cached (x, read-only).
__device__ __forceinline__ int4v ld16_ag(const unsigned short* p) {
  int4v r;
  asm volatile("global_load_dwordx4 %0, %1, off sc1"
               : "=v"(r) : "v"(p) : "memory");
  return r;
}
__device__ __forceinline__ int4v ld16_nc(const float* p) {
  int4v r;
  asm volatile("global_load_dwordx4 %0, %1, off"
               : "=v"(r) : "v"(p) : "memory");
  return r;
}
__device__ __forceinline__ void store2_ag(unsigned short* p, unsigned short v) {
  asm volatile("global_store_short %0, %1, off sc1"
               :: "v"(p), "v"((u32)v) : "memory");
}
__device__ __forceinline__ void store4_ag(u32* p, u32 v) {
  asm volatile("global_store_dword %0, %1, off sc1"
               :: "v"(p), "v"(v) : "memory");
}

__device__ __forceinline__ float sigf(float z) {
  return __builtin_amdgcn_rcpf(1.f + __expf(-z));
}
__device__ __forceinline__ float tanh_fast(float v) {
  const float e = __expf(-2.f * fabsf(v));
  const float r = (1.f - e) * __builtin_amdgcn_rcpf(1.f + e);
  return copysignf(r, v);
}

extern "C" __global__ void __launch_bounds__(NTHR, 1)
lstm_persistent(const float* __restrict__ x,
                const float* __restrict__ Wk,
                const float* __restrict__ Rk,
                const float* __restrict__ bias,
                float* __restrict__ out,
                unsigned short* __restrict__ hbuf,  // [2][64][512] bf16
                u32* __restrict__ tags)             // [4][64][16] spread
{
  extern __shared__ char smem[];
  unsigned short* wf = (unsigned short*)smem;      // [tile][kt][lane][8]

  const int bid = blockIdx.x;
  const int tid = threadIdx.x;
  const int w   = tid >> 6;        // wave = output tile
  const int l   = tid & 63;
  const int g   = bid & 3;         // row group on XCD pair {g, g+4}
  const int m   = bid >> 2;        // u-cols 8m..8m+7

  // ---- one-time weight staging; col n of tile tau: gate=n>>2, u'=n&3 ----
  for (int i = tid; i < WF_ELEMS; i += NTHR) {
    const int j    = i & 7;
    const int lane = (i >> 3) & 63;
    const int kt   = (i >> 9) % 24;
    const int tau  = (i >> 9) / 24;
    const int k    = kt * 32 + ((lane >> 4) << 3) + j;     // 0..767
    const int n    = lane & 15;
    const int zc   = (n >> 2) * Uu + m * 8 + tau * 4 + (n & 3);
    const float v  = (k < 256) ? Wk[(size_t)k * G4U + zc]
                               : Rk[(size_t)(k - 256) * G4U + zc];
    wf[i] = f2bf(v);
  }
  __syncthreads();

  // ---- x-part weight frags for own tile (kt 0..7; 32 VGPR) ----
  bf16x8 wfx[8];
  #pragma unroll
  for (int q = 0; q < 8; ++q)
    wfx[q] = *(const bf16x8*)(wf + ((w * 24 + q) * 64 + l) * 8);

  // ---- role constants ----
  const int n15   = l & 15;
  const float blane = bias[(n15 >> 2) * Uu + m * 8 + w * 4 + (n15 & 3)];
  const int sbase = (l & 48) + (l & 3);        // shfl base (gate stride 4)
  const bool gm   = (n15 < 4);                 // gate-math lane
  const int u_out = m * 8 + w * 4 + (l & 3);   // valid for gm lanes
  const int b_row0 = g * 16 + (l >> 4) * 4;    // gm lane's rows b_row0..+3
  float creg[4] = {0.f, 0.f, 0.f, 0.f};

  const int b_ld = g * 16 + n15;               // A-frag row
  const int kq   = (l >> 4) * 8;
  const u32* tagp = tags + ((size_t)g * 64 + l) * TAGSTRIDE;

  // ---- pre-loop: prefetch x(t=0); issue + drain initial probe ----
  int4v xv[8][2];
  {
    const float* xp0 = x + (size_t)b_ld * Tt * 256 + kq;
    #pragma unroll
    for (int q = 0; q < 8; ++q) {
      xv[q][0] = ld16_nc(xp0 + q * 32);
      xv[q][1] = ld16_nc(xp0 + q * 32 + 4);
    }
  }
  u32 tv = 0;
  if (w == 0)
    asm volatile("global_load_dword %0, %1, off sc1"
                 : "=v"(tv) : "v"(tagp) : "memory");
  asm volatile("s_waitcnt vmcnt(0)" ::: "memory");
  __builtin_amdgcn_sched_barrier(0);

  for (int t = 0; t < Tt; ++t) {
    // ---- x phase: pure cvt + 8 MFMAs into the single acc chain ----
    f32x4 acc = {0.f, 0.f, 0.f, 0.f};
    #pragma unroll
    for (int q = 0; q < 8; ++q) {
      const f32x4 v0 = __builtin_bit_cast(f32x4, xv[q][0]);
      const f32x4 v1 = __builtin_bit_cast(f32x4, xv[q][1]);
      int r0, r1, r2, r3;
      asm("v_cvt_pk_bf16_f32 %0, %1, %2" : "=v"(r0) : "v"(v0[0]), "v"(v0[1]));
      asm("v_cvt_pk_bf16_f32 %0, %1, %2" : "=v"(r1) : "v"(v0[2]), "v"(v0[3]));
      asm("v_cvt_pk_bf16_f32 %0, %1, %2" : "=v"(r2) : "v"(v1[0]), "v"(v1[1]));
      asm("v_cvt_pk_bf16_f32 %0, %1, %2" : "=v"(r3) : "v"(v1[2]), "v"(v1[3]));
      const int4v ai = {r0, r1, r2, r3};
      const bf16x8 a = __builtin_bit_cast(bf16x8, ai);
      acc = __builtin_amdgcn_mfma_f32_16x16x32_bf16(a, wfx[q], acc, 0, 0, 0);
    }

    // ---- acquire: wave 0 checks prior probe via counted vmcnt(4) ----
    // (w0 pending, issue order: tag(1), probe(1), out(4) -> vmcnt(4)
    //  certifies tag+probe retired while out acks may stay pending)
    if (w == 0) {
      asm volatile("s_waitcnt vmcnt(4)" ::: "memory");
      __builtin_amdgcn_sched_barrier(0);
      while (!__all(tv >= (u32)t)) {
        __builtin_amdgcn_s_sleep(1);
        asm volatile("global_load_dword %0, %1, off sc1\n\ts_waitcnt vmcnt(0)"
                     : "=v"(tv) : "v"(tagp) : "memory");
        __builtin_amdgcn_sched_barrier(0);
      }
    }
    __builtin_amdgcn_s_barrier();                // hand-off: tags observed
    __builtin_amdgcn_sched_barrier(0);

    // ---- h data loads (full K: 16 frags), then x prefetch for t+1 ----
    const unsigned short* hrow =
        hbuf + ((size_t)(t & 1) * 64 + b_ld) * Uu + kq;
    int4v hf[16];
    #pragma unroll
    for (int q = 0; q < 16; ++q)
      hf[q] = ld16_ag(hrow + q * 32);
    {
      const int tn = (t + 1 < Tt) ? t + 1 : t;   // clamp: avoid OOB read
      const float* xpn = x + ((size_t)b_ld * Tt + tn) * 256 + kq;
      #pragma unroll
      for (int q = 0; q < 8; ++q) {
        xv[q][0] = ld16_nc(xpn + q * 32);
        xv[q][1] = ld16_nc(xpn + q * 32 + 4);
      }
    }

    // ---- split drain + 16 h MFMAs (outs+h are oldest; x-pf stays out) ----
    asm volatile("s_waitcnt vmcnt(24)" ::: "memory");  // out(<=4)+hf[0..7] done
    __builtin_amdgcn_sched_barrier(0);
    #pragma unroll
    for (int q = 0; q < 8; ++q) {
      const bf16x8 a = __builtin_bit_cast(bf16x8, hf[q]);
      const bf16x8 b = *(const bf16x8*)(wf + ((w * 24 + 8 + q) * 64 + l) * 8);
      acc = __builtin_amdgcn_mfma_f32_16x16x32_bf16(a, b, acc, 0, 0, 0);
    }
    asm volatile("s_waitcnt vmcnt(16)" ::: "memory");  // hf[8..15] done
    __builtin_amdgcn_sched_barrier(0);
    #pragma unroll
    for (int q = 8; q < 16; ++q) {
      const bf16x8 a = __builtin_bit_cast(bf16x8, hf[q]);
      const bf16x8 b = *(const bf16x8*)(wf + ((w * 24 + 8 + q) * 64 + l) * 8);
      acc = __builtin_amdgcn_mfma_f32_16x16x32_bf16(a, b, acc, 0, 0, 0);
    }

    // ---- gate math via cross-lane shfl (no LDS, no barrier) ----
    float hv[4];
    {
      f32x4 zv;
      #pragma unroll
      for (int r = 0; r < 4; ++r) zv[r] = acc[r] + blane;
      #pragma unroll
      for (int r = 0; r < 4; ++r) {
        const float zi = __shfl(zv[r], sbase + 0, 64);
        const float zf = __shfl(zv[r], sbase + 4, 64);
        const float zc = __shfl(zv[r], sbase + 8, 64);
        const float zo = __shfl(zv[r], sbase + 12, 64);
        const float ig = sigf(zi);
        const float fg = sigf(zf);
        const float og = sigf(zo);
        const float cc = fg * creg[r] + ig * zc;
        creg[r] = cc;
        hv[r] = og * cc;
      }
    }

    // ---- release: h stores -> ack -> barrier -> tag -> probe -> out ----
    if (gm) {
      #pragma unroll
      for (int r = 0; r < 4; ++r)
        store2_ag(hbuf + ((size_t)(((t + 1) & 1)) * 64 + b_row0 + r) * Uu
                       + u_out, f2bf(hv[r]));
    }
    asm volatile("s_waitcnt vmcnt(0)" ::: "memory");   // h ack (+x-pf done)
    __builtin_amdgcn_sched_barrier(0);
    __builtin_amdgcn_s_barrier();                // both waves' h at IF$
    __builtin_amdgcn_sched_barrier(0);
    if (tid == 0)
      store4_ag(tags + ((size_t)g * 64 + m) * TAGSTRIDE, (u32)(t + 1));
    if (w == 0)
      asm volatile("global_load_dword %0, %1, off sc1"
                   : "=v"(tv) : "v"(tagp) : "memory");  // probe BEFORE out
    if (gm) {
      #pragma unroll
      for (int r = 0; r < 4; ++r) {
        const float ov = tanh_fast(hv[r]);
        float* op = out + ((size_t)(b_row0 + r) * Tt + t) * Uu + u_out;
        asm volatile("global_store_dword %0, %1, off nt"
                     :: "v"(op), "v"(ov) : "memory");   // slow acks stay last
      }
    }
  }
}

extern "C" void kernel_launch(void* const* d_in, const int* in_sizes, int n_in,
                              void* d_out, int out_size, void* d_ws, size_t ws_size,
                              hipStream_t stream) {
  const float* x    = (const float*)d_in[0];
  const float* Wk   = (const float*)d_in[1];
  const float* Rk   = (const float*)d_in[2];
  const float* bias = (const float*)d_in[3];
  float* out = (float*)d_out;
  unsigned short* hbuf = (unsigned short*)d_ws;
  u32* tags = (u32*)((char*)d_ws + (size_t)2 * 64 * Uu * sizeof(unsigned short));

  // zeroed hbuf = h_0 = 0 (both parities); tags 0 = "h_0 published".
  (void)hipMemsetAsync(d_ws, 0,
                       (size_t)2 * 64 * Uu * sizeof(unsigned short)
                         + (size_t)4 * 64 * TAGSTRIDE * sizeof(u32),
                       stream);

  (void)hipFuncSetAttribute((const void*)lstm_persistent,
                            hipFuncAttributeMaxDynamicSharedMemorySize,
                            SMEM_BYTES);

  hipLaunchKernelGGL(lstm_persistent, dim3(NWG), dim3(NTHR), SMEM_BYTES, stream,
                     x, Wk, Rk, bias, out, hbuf, tags);
}

// Round 20
// 2754.411 us; speedup vs baseline: 1.4333x; 1.4333x over previous
//
#include <hip/hip_runtime.h>
#include <stdint.h>

// Persistent-LSTM, round 20 = round 15 VERBATIM (the measured optimum,
// 2752 us). Restores the best state after r16/r18/r19 experiments regressed.
//
// Why this is the basin bottom (19-round ablation summary):
//  - Exchange protocol: release/acquire with ack->barrier->tag (this kernel)
//    beats: per-word tags+polling (r9: poll churn), no-ack fire-and-forget
//    (r16: tag beats data, validation churn), speculative reads (r14, r18:
//    spec loses the producer race), flag-first 2-hop (r7: serial hops),
//    LDS-coalesced release (r13: staging round-trip > ack savings).
//  - Coherence point: IF$ via sc1 is the ONLY safe one. sc0 stores linger
//    CU-local -> intra-XCD L2 messaging deadlocks (r3, r17, both hung).
//    System scope (sc0 sc1) round-trips HBM (r2: 1.4 GB FETCH).
//  - Topology: XCD-pair grouping (g=bid&3) keeps x-reads 2-L2-local
//    (FETCH 1.1 GB -> 190 MB, r9); full-XCD groups add outlier risk.
//  - Compute: K-split waves + zbuf parity double-buffer beats tile-split
//    waves + shfl gather (r19: 2x h-reads, 1.4x WRITE amplification).
//  - Serial chain surgery (this kernel's r15 deltas): counted-vmcnt poll
//    head (out-store ack never blocks the probe), x register-prefetch one
//    step ahead (x-phase = pure cvt+MFMA), split h-certify (vmcnt 12/8),
//    probe-before-out tail ordering.
// Remaining 2.7 us/step = T*(L+C) with L ~= 2 IF$ round-trips + ack +
// barrier; wall-clock-serial per recurrence step, not hideable by any
// schedule. This is a synchronization-latency floor, not a BW/compute one.

#define Tt   1024
#define Uu   512
#define G4U  2048
#define NWG  256
#define NTHR 128
#define TAGSTRIDE 16                               // u32s per tag line (64 B)

#define WF_ELEMS (2 * 24 * 64 * 8)                 // 24576 bf16 = 48 KB
#define WF_BYTES (WF_ELEMS * 2)
#define ZB_PLANE (16 * 17)
#define ZB_HALF  (4 * ZB_PLANE)                    // floats per parity buffer
#define SMEM_BYTES (WF_BYTES + 2 * ZB_HALF * 4)    // 48 KB + 8704 B

typedef short  bf16x8 __attribute__((ext_vector_type(8)));
typedef float  f32x4  __attribute__((ext_vector_type(4)));
typedef int    int4v  __attribute__((ext_vector_type(4)));
typedef unsigned int u32;

__device__ __forceinline__ unsigned short f2bf(float f) {
  u32 u = __builtin_bit_cast(u32, f);
  u += 0x7fffu + ((u >> 16) & 1u);                 // RNE (finite inputs)
  return (unsigned short)(u >> 16);
}

// sc1 = agent scope (IF$); plain = cached (x, read-only).
__device__ __forceinline__ int4v ld16_ag(const unsigned short* p) {
  int4v r;
  asm volatile("global_load_dwordx4 %0, %1, off sc1"
               : "=v"(r) : "v"(p) : "memory");
  return r;
}
__device__ __forceinline__ int4v ld16_nc(const float* p) {
  int4v r;
  asm volatile("global_load_dwordx4 %0, %1, off"
               : "=v"(r) : "v"(p) : "memory");
  return r;
}
__device__ __forceinline__ void store2_ag(unsigned short* p, unsigned short v) {
  asm volatile("global_store_short %0, %1, off sc1"
               :: "v"(p), "v"((u32)v) : "memory");
}
__device__ __forceinline__ void store4_ag(u32* p, u32 v) {
  asm volatile("global_store_dword %0, %1, off sc1"
               :: "v"(p), "v"(v) : "memory");
}

__device__ __forceinline__ float sigf(float z) {
  return __builtin_amdgcn_rcpf(1.f + __expf(-z));
}
__device__ __forceinline__ float tanh_fast(float v) {
  const float e = __expf(-2.f * fabsf(v));
  const float r = (1.f - e) * __builtin_amdgcn_rcpf(1.f + e);
  return copysignf(r, v);
}

extern "C" __global__ void __launch_bounds__(NTHR, 1)
lstm_persistent(const float* __restrict__ x,
                const float* __restrict__ Wk,
                const float* __restrict__ Rk,
                const float* __restrict__ bias,
                float* __restrict__ out,
                unsigned short* __restrict__ hbuf,  // [2][64][512] bf16
                u32* __restrict__ tags)             // [4][64][16] spread
{
  extern __shared__ char smem[];
  unsigned short* wf   = (unsigned short*)smem;            // [nt][kt][lane][8]
  float*          zbuf = (float*)(smem + WF_BYTES);        // [2][w*nt][16][17]

  const int bid = blockIdx.x;
  const int tid = threadIdx.x;
  const int w   = tid >> 6;
  const int l   = tid & 63;
  const int g   = bid & 3;         // row group on XCD pair {g, g+4}
  const int m   = bid >> 2;        // u-cols 8m..8m+7

  // ---- one-time weight staging into MFMA B-fragment order ----
  for (int i = tid; i < WF_ELEMS; i += NTHR) {
    const int j    = i & 7;
    const int lane = (i >> 3) & 63;
    const int kt   = (i >> 9) % 24;
    const int nt   = (i >> 9) / 24;
    const int k    = kt * 32 + ((lane >> 4) << 3) + j;     // 0..767
    const int n    = nt * 16 + (lane & 15);                // 0..31
    const int zc   = (n >> 3) * Uu + m * 8 + (n & 7);      // gate*512 + u
    const float v  = (k < 256) ? Wk[(size_t)k * G4U + zc]
                               : Rk[(size_t)(k - 256) * G4U + zc];
    wf[i] = f2bf(v);
  }
  __syncthreads();

  // ---- preload x-part weight fragments (kt = 2q+w, q=0..3) ----
  bf16x8 wfx[4][2];
  #pragma unroll
  for (int q = 0; q < 4; ++q)
    #pragma unroll
    for (int nt = 0; nt < 2; ++nt)
      wfx[q][nt] = *(const bf16x8*)(wf + (((nt * 24) + (2 * q + w)) * 64 + l) * 8);

  // ---- combine-role constants (one (row,u) pair per thread) ----
  const int row_c = tid >> 3;                  // 0..15
  const int uu    = tid & 7;
  const int b_out = g * 16 + row_c;
  const int u_out = m * 8 + uu;
  float breg[4];
  #pragma unroll
  for (int gg = 0; gg < 4; ++gg) breg[gg] = bias[gg * Uu + u_out];
  float creg = 0.f;

  // ---- load-role constants (lane-level, MFMA A-fragment) ----
  const int b_ld = g * 16 + (l & 15);
  const int kq   = (l >> 4) * 8;
  const u32* tagp = tags + ((size_t)g * 64 + l) * TAGSTRIDE;  // producer l's line

  // ---- pre-loop: prefetch x(t=0); issue + drain initial probe ----
  int4v xv[4][2];
  {
    const float* xp0 = x + ((size_t)b_ld * Tt + 0) * 256 + kq;
    #pragma unroll
    for (int q = 0; q < 4; ++q) {
      const int kt = 2 * q + w;
      xv[q][0] = ld16_nc(xp0 + kt * 32);
      xv[q][1] = ld16_nc(xp0 + kt * 32 + 4);
    }
  }
  u32 tv = 0;
  if (w == 0)
    asm volatile("global_load_dword %0, %1, off sc1"
                 : "=v"(tv) : "v"(tagp) : "memory");
  asm volatile("s_waitcnt vmcnt(0)" ::: "memory");
  __builtin_amdgcn_sched_barrier(0);

  for (int t = 0; t < Tt; ++t) {
    // ---- x phase: pure cvt + 8 MFMAs (x regs prefetched & certified) ----
    f32x4 aX0 = {0.f, 0.f, 0.f, 0.f};
    f32x4 aX1 = {0.f, 0.f, 0.f, 0.f};
    #pragma unroll
    for (int q = 0; q < 4; ++q) {
      const f32x4 v0 = __builtin_bit_cast(f32x4, xv[q][0]);
      const f32x4 v1 = __builtin_bit_cast(f32x4, xv[q][1]);
      int r0, r1, r2, r3;
      asm("v_cvt_pk_bf16_f32 %0, %1, %2" : "=v"(r0) : "v"(v0[0]), "v"(v0[1]));
      asm("v_cvt_pk_bf16_f32 %0, %1, %2" : "=v"(r1) : "v"(v0[2]), "v"(v0[3]));
      asm("v_cvt_pk_bf16_f32 %0, %1, %2" : "=v"(r2) : "v"(v1[0]), "v"(v1[1]));
      asm("v_cvt_pk_bf16_f32 %0, %1, %2" : "=v"(r3) : "v"(v1[2]), "v"(v1[3]));
      const int4v ai = {r0, r1, r2, r3};
      const bf16x8 a = __builtin_bit_cast(bf16x8, ai);
      aX0 = __builtin_amdgcn_mfma_f32_16x16x32_bf16(a, wfx[q][0], aX0, 0, 0, 0);
      aX1 = __builtin_amdgcn_mfma_f32_16x16x32_bf16(a, wfx[q][1], aX1, 0, 0, 0);
    }

    // ---- acquire: wave 0 checks prior probe via COUNTED vmcnt(1) ----
    // (outstanding, issue order: [tag store (lane0) <], probe, out store ->
    //  in-order retire means vmcnt(1) certifies the probe while the slow
    //  out-store ack stays pending)
    if (w == 0) {
      asm volatile("s_waitcnt vmcnt(1)" ::: "memory");
      __builtin_amdgcn_sched_barrier(0);
      while (!__all(tv >= (u32)t)) {
        __builtin_amdgcn_s_sleep(1);
        asm volatile("global_load_dword %0, %1, off sc1\n\ts_waitcnt vmcnt(0)"
                     : "=v"(tv) : "v"(tagp) : "memory");
        __builtin_amdgcn_sched_barrier(0);
      }
    }
    __builtin_amdgcn_s_barrier();                // hand-off: tags observed
    __builtin_amdgcn_sched_barrier(0);

    // ---- h data loads (after tag pass), then x prefetch for t+1 ----
    const unsigned short* hrow =
        hbuf + ((size_t)(t & 1) * 64 + b_ld) * Uu + kq;
    int4v hf[8];
    #pragma unroll
    for (int q = 0; q < 8; ++q)
      hf[q] = ld16_ag(hrow + (2 * q + w) * 32);
    {
      const int tn = (t + 1 < Tt) ? t + 1 : t;   // clamp: avoid OOB read
      const float* xpn = x + ((size_t)b_ld * Tt + tn) * 256 + kq;
      #pragma unroll
      for (int q = 0; q < 4; ++q) {
        const int kt = 2 * q + w;
        xv[q][0] = ld16_nc(xpn + kt * 32);
        xv[q][1] = ld16_nc(xpn + kt * 32 + 4);
      }
    }

    // ---- split drain + h MFMAs (h loads are the oldest 8 in the queue) ----
    f32x4 aH0 = {0.f, 0.f, 0.f, 0.f};
    f32x4 aH1 = {0.f, 0.f, 0.f, 0.f};
    asm volatile("s_waitcnt vmcnt(12)" ::: "memory");  // hf[0..3] done
    __builtin_amdgcn_sched_barrier(0);
    #pragma unroll
    for (int q = 0; q < 4; ++q) {
      const int kt = 8 + 2 * q + w;
      const bf16x8 a = __builtin_bit_cast(bf16x8, hf[q]);
      const bf16x8 b0 = *(const bf16x8*)(wf + ((0 * 24 + kt) * 64 + l) * 8);
      const bf16x8 b1 = *(const bf16x8*)(wf + ((1 * 24 + kt) * 64 + l) * 8);
      aH0 = __builtin_amdgcn_mfma_f32_16x16x32_bf16(a, b0, aH0, 0, 0, 0);
      aH1 = __builtin_amdgcn_mfma_f32_16x16x32_bf16(a, b1, aH1, 0, 0, 0);
    }
    asm volatile("s_waitcnt vmcnt(8)" ::: "memory");   // hf[4..7] done
    __builtin_amdgcn_sched_barrier(0);
    #pragma unroll
    for (int q = 4; q < 8; ++q) {
      const int kt = 8 + 2 * q + w;
      const bf16x8 a = __builtin_bit_cast(bf16x8, hf[q]);
      const bf16x8 b0 = *(const bf16x8*)(wf + ((0 * 24 + kt) * 64 + l) * 8);
      const bf16x8 b1 = *(const bf16x8*)(wf + ((1 * 24 + kt) * 64 + l) * 8);
      aH0 = __builtin_amdgcn_mfma_f32_16x16x32_bf16(a, b0, aH0, 0, 0, 0);
      aH1 = __builtin_amdgcn_mfma_f32_16x16x32_bf16(a, b1, aH1, 0, 0, 0);
    }

    const f32x4 z0 = aX0 + aH0;
    const f32x4 z1 = aX1 + aH1;

    // ---- z reduce through parity-double-buffered zbuf (1 barrier) ----
    float* zb = zbuf + (t & 1) * ZB_HALF;
    {
      float* zw = zb + ((w * 2 + 0) * 16 + (l >> 4) * 4) * 17 + (l & 15);
      #pragma unroll
      for (int r = 0; r < 4; ++r) {
        zw[r * 17]           = z0[r];
        zw[r * 17 + 16 * 17] = z1[r];            // nt=1 plane
      }
    }
    __syncthreads();

    // ---- gate math (fp32), cell update ----
    float z[4];
    #pragma unroll
    for (int gg = 0; gg < 4; ++gg) {
      const int n  = gg * 8 + uu;
      const int nt = n >> 4, nc = n & 15;
      z[gg] = zb[((0 + nt) * 16 + row_c) * 17 + nc]
            + zb[((2 + nt) * 16 + row_c) * 17 + nc]
            + breg[gg];
    }
    const float ig = sigf(z[0]);
    const float fg = sigf(z[1]);
    const float og = sigf(z[3]);
    const float cc = fg * creg + ig * z[2];
    creg = cc;
    const float hh = og * cc;

    // ---- release: h store -> ack -> barrier -> tag -> probe -> out ----
    store2_ag(hbuf + ((size_t)((t + 1) & 1) * 64 + b_out) * Uu + u_out,
              f2bf(hh));
    asm volatile("s_waitcnt vmcnt(0)" ::: "memory");   // h ack (+x-pf certified)
    __builtin_amdgcn_sched_barrier(0);
    __builtin_amdgcn_s_barrier();                // all 128 producers drained
    __builtin_amdgcn_sched_barrier(0);
    if (tid == 0)
      store4_ag(tags + ((size_t)g * 64 + m) * TAGSTRIDE, (u32)(t + 1));
    if (w == 0)
      asm volatile("global_load_dword %0, %1, off sc1"
                   : "=v"(tv) : "v"(tagp) : "memory");  // next probe BEFORE out
    {
      const float ov = tanh_fast(hh);
      float* op = out + ((size_t)b_out * Tt + t) * Uu + u_out;
      asm volatile("global_store_dword %0, %1, off nt"
                   :: "v"(op), "v"(ov) : "memory");     // slow ack stays behind probe
    }
  }
}

extern "C" void kernel_launch(void* const* d_in, const int* in_sizes, int n_in,
                              void* d_out, int out_size, void* d_ws, size_t ws_size,
                              hipStream_t stream) {
  const float* x    = (const float*)d_in[0];
  const float* Wk   = (const float*)d_in[1];
  const float* Rk   = (const float*)d_in[2];
  const float* bias = (const float*)d_in[3];
  float* out = (float*)d_out;
  unsigned short* hbuf = (unsigned short*)d_ws;
  u32* tags = (u32*)((char*)d_ws + (size_t)2 * 64 * Uu * sizeof(unsigned short));

  // zeroed hbuf = h_0 = 0 (both parities); tags 0 = "h_0 published".
  (void)hipMemsetAsync(d_ws, 0,
                       (size_t)2 * 64 * Uu * sizeof(unsigned short)
                         + (size_t)4 * 64 * TAGSTRIDE * sizeof(u32),
                       stream);

  (void)hipFuncSetAttribute((const void*)lstm_persistent,
                            hipFuncAttributeMaxDynamicSharedMemorySize,
                            SMEM_BYTES);

  hipLaunchKernelGGL(lstm_persistent, dim3(NWG), dim3(NTHR), SMEM_BYTES, stream,
                     x, Wk, Rk, bias, out, hbuf, tags);
}